// Round 1
// baseline (125853.870 us; speedup 1.0000x reference)
//
#include <hip/hip_runtime.h>
#include <stdint.h>

#define SEQ   512
#define BATCH 64
#define INP   64
#define HID   1024
#define NBLK  512     // 256 layer-0 blocks + 256 layer-1 blocks (wavefront pipeline)
#define NTHR  256     // 4 units x 64 batch

// ---- grid-wide barrier: flag-array, poison-safe, device-scope (unchanged, proven) ----
__device__ __forceinline__ void gbar(uint32_t* flags, uint32_t val, int tid) {
    __syncthreads();   // drains all block stores + exec sync
    if (tid == 0) {
        __threadfence();   // release: make this XCD's dirty lines visible at coherence point
        __hip_atomic_store(&flags[blockIdx.x], val, __ATOMIC_RELAXED, __HIP_MEMORY_SCOPE_AGENT);
    }
    if (tid < 64) {
        for (;;) {
            bool ok = true;
            #pragma unroll
            for (int i = 0; i < NBLK / 64; ++i) {
                uint32_t v = __hip_atomic_load(&flags[tid + i * 64], __ATOMIC_RELAXED,
                                               __HIP_MEMORY_SCOPE_AGENT);
                // pass iff val <= v < val + 2^28  (0xAAAAAAAA poison and stale values fail)
                ok &= ((uint32_t)(v - val) < 0x10000000u);
            }
            if (__all(ok)) break;
        }
    }
    if (tid == 0) __threadfence();  // acquire: invalidate caches so fresh h is read
    __syncthreads();
}

__device__ __forceinline__ float sigf(float x) { return 1.0f / (1.0f + __expf(-x)); }

// ============ fused wavefront kernel ============
// blocks 0..255   : layer 0, units 4*bk   + u, compute step t at round t   (compute, then bar)
// blocks 256..511 : layer 1, units 4*(bk-256)+u, compute step t at round t+1 (bar, then compute)
// Both branches post identical barrier values 1,2,...,513 -> 1-step pipeline skew.
// h1_t parked in d_out[t]; layer-1 overwrites d_out[t] with h2_t DEFERRED (at round t+2).
__global__ void __launch_bounds__(NTHR, 2) lstm_fused(
    const float* __restrict__ x,
    const float* __restrict__ Wih0, const float* __restrict__ Whh0,
    const float* __restrict__ bih0, const float* __restrict__ bhh0,
    const float* __restrict__ Wih1, const float* __restrict__ Whh1,
    const float* __restrict__ bih1, const float* __restrict__ bhh1,
    float* __restrict__ out, float* __restrict__ h0buf, float* __restrict__ h2buf,
    uint32_t* __restrict__ flags)
{
    __shared__ float Wsh[4][HID][4];   // 64 KB exactly: Whh0 (L0 blocks) or Whh1 (L1 blocks)
    const int tid = threadIdx.x;
    const int bk  = blockIdx.x;
    const bool L1 = (bk >= NBLK / 2);
    const int ub  = (L1 ? bk - NBLK / 2 : bk) * 4;                 // first unit of block
    const int u   = __builtin_amdgcn_readfirstlane(tid >> 6);      // wave-uniform unit index
    const int b   = tid & 63;
    const int j   = ub + u;

    // stage recurrent weights (coalesced over k)
    const float* Whh = L1 ? Whh1 : Whh0;
    for (int idx = tid; idx < 4 * 4 * HID; idx += NTHR) {
        int uu = idx >> 12, g = (idx >> 10) & 3, k = idx & (HID - 1);
        Wsh[uu][k][g] = Whh[((size_t)(g * HID + ub + uu)) * HID + k];
    }
    const float* bi = L1 ? bih1 : bih0;
    const float* bh = L1 ? bhh1 : bhh0;
    const float bias0 = bi[0 * HID + j] + bh[0 * HID + j];
    const float bias1 = bi[1 * HID + j] + bh[1 * HID + j];
    const float bias2 = bi[2 * HID + j] + bh[2 * HID + j];
    const float bias3 = bi[3 * HID + j] + bh[3 * HID + j];

    float* hbuf = L1 ? h2buf : h0buf;
    hbuf[j * 64 + b] = 0.0f;            // h(-1) = 0 in slot 0 (ws is poisoned)
    float c = 0.0f, hout = 0.0f;
    gbar(flags, 1u, tid);

    if (!L1) {
        // ---- layer 0: compute step t, then barrier(t+2) ----
        const float4* wi0 = (const float4*)(Wih0 + (size_t)(0 * HID + j) * INP);
        const float4* wi1 = (const float4*)(Wih0 + (size_t)(1 * HID + j) * INP);
        const float4* wi2 = (const float4*)(Wih0 + (size_t)(2 * HID + j) * INP);
        const float4* wi3 = (const float4*)(Wih0 + (size_t)(3 * HID + j) * INP);
        for (int t = 0; t < SEQ; ++t) {
            float a0 = bias0, a1 = bias1, a2 = bias2, a3 = bias3;
            const float4* xr = (const float4*)(x + ((size_t)t * BATCH + b) * INP);
            #pragma unroll
            for (int k4 = 0; k4 < INP / 4; ++k4) {
                float4 xv = xr[k4];
                float4 u0 = wi0[k4], u1 = wi1[k4], u2 = wi2[k4], u3 = wi3[k4];
                a0 += u0.x * xv.x; a1 += u1.x * xv.x; a2 += u2.x * xv.x; a3 += u3.x * xv.x;
                a0 += u0.y * xv.y; a1 += u1.y * xv.y; a2 += u2.y * xv.y; a3 += u3.y * xv.y;
                a0 += u0.z * xv.z; a1 += u1.z * xv.z; a2 += u2.z * xv.z; a3 += u3.z * xv.z;
                a0 += u0.w * xv.w; a1 += u1.w * xv.w; a2 += u2.w * xv.w; a3 += u3.w * xv.w;
            }
            const float* hr = h0buf + (t & 1) * (HID * 64);
            float*       hw = h0buf + ((t & 1) ^ 1) * (HID * 64);
            #pragma unroll 16
            for (int k = 0; k < HID; ++k) {
                float  hv = hr[k * 64 + b];
                float4 w  = *(const float4*)&Wsh[u][k][0];
                a0 += w.x * hv; a1 += w.y * hv; a2 += w.z * hv; a3 += w.w * hv;
            }
            float ig = sigf(a0), fg = sigf(a1), gg = tanhf(a2), og = sigf(a3);
            c = fg * c + ig * gg;
            float h = og * tanhf(c);
            hw[j * 64 + b] = h;
            out[((size_t)t * BATCH + b) * HID + j] = h;   // park h1_t in d_out[t]
            gbar(flags, (uint32_t)(t + 2), tid);
        }
    } else {
        // ---- layer 1: barrier(t+2) (waits for L0's step t), then compute step t ----
        const float4* wr0 = (const float4*)(Wih1 + (size_t)(0 * HID + j) * HID);
        const float4* wr1 = (const float4*)(Wih1 + (size_t)(1 * HID + j) * HID);
        const float4* wr2 = (const float4*)(Wih1 + (size_t)(2 * HID + j) * HID);
        const float4* wr3 = (const float4*)(Wih1 + (size_t)(3 * HID + j) * HID);
        for (int t = 0; t < SEQ; ++t) {
            gbar(flags, (uint32_t)(t + 2), tid);
            // deferred h2 write: all reads of h1[t-1] completed before this barrier
            if (t > 0) out[((size_t)(t - 1) * BATCH + b) * HID + j] = hout;
            float a0 = bias0, a1 = bias1, a2 = bias2, a3 = bias3;
            // x-part: h1_t parked in d_out[t]; weight rows are wave-uniform (s_load path)
            const float4* xr = (const float4*)(out + ((size_t)t * BATCH + b) * HID);
            #pragma unroll 8
            for (int k4 = 0; k4 < HID / 4; ++k4) {
                float4 xv = xr[k4];
                float4 u0 = wr0[k4], u1 = wr1[k4], u2 = wr2[k4], u3 = wr3[k4];
                a0 += u0.x * xv.x; a1 += u1.x * xv.x; a2 += u2.x * xv.x; a3 += u3.x * xv.x;
                a0 += u0.y * xv.y; a1 += u1.y * xv.y; a2 += u2.y * xv.y; a3 += u3.y * xv.y;
                a0 += u0.z * xv.z; a1 += u1.z * xv.z; a2 += u2.z * xv.z; a3 += u3.z * xv.z;
                a0 += u0.w * xv.w; a1 += u1.w * xv.w; a2 += u2.w * xv.w; a3 += u3.w * xv.w;
            }
            const float* hr = h2buf + (t & 1) * (HID * 64);
            float*       hw = h2buf + ((t & 1) ^ 1) * (HID * 64);
            #pragma unroll 16
            for (int k = 0; k < HID; ++k) {
                float  hv = hr[k * 64 + b];
                float4 w  = *(const float4*)&Wsh[u][k][0];
                a0 += w.x * hv; a1 += w.y * hv; a2 += w.z * hv; a3 += w.w * hv;
            }
            float ig = sigf(a0), fg = sigf(a1), gg = tanhf(a2), og = sigf(a3);
            c = fg * c + ig * gg;
            float h = og * tanhf(c);
            hw[j * 64 + b] = h;
            hout = h;
            // no trailing barrier on t==SEQ-1: kernel end is the release
        }
        // out[SEQ-1] (h2) and y_pred are written by the epilogue kernel (no extra round)
    }
}

// ============ epilogue: out[T-1] = h2[T-1], y_pred = h2[T-1] @ Wlin^T + b ============
// h2[T-1] lives in h2buf slot 0 (((SEQ-1)&1)^1 == 0). Kernel boundary = the barrier.
__global__ void lstm_finalize(const float* __restrict__ Wlin, const float* __restrict__ blin,
                              float* __restrict__ out, const float* __restrict__ h2buf)
{
    __shared__ float red[256];
    const int b = blockIdx.x, tid = threadIdx.x;
    for (int jj = tid; jj < HID; jj += 256)
        out[((size_t)(SEQ - 1) * BATCH + b) * HID + jj] = h2buf[jj * 64 + b];
    float p = 0.0f;
    for (int k = tid; k < HID; k += 256) p += h2buf[k * 64 + b] * Wlin[k];
    red[tid] = p;
    __syncthreads();
    for (int s = 128; s > 0; s >>= 1) {
        if (tid < s) red[tid] += red[tid + s];
        __syncthreads();
    }
    if (tid == 0) out[(size_t)SEQ * BATCH * HID + b] = blin[0] + red[0];
}

extern "C" void kernel_launch(void* const* d_in, const int* in_sizes, int n_in,
                              void* d_out, int out_size, void* d_ws, size_t ws_size,
                              hipStream_t stream) {
    const float* x     = (const float*)d_in[0];
    const float* Wih0  = (const float*)d_in[1];
    const float* Whh0  = (const float*)d_in[2];
    const float* bih0  = (const float*)d_in[3];
    const float* bhh0  = (const float*)d_in[4];
    const float* Wih1  = (const float*)d_in[5];
    const float* Whh1  = (const float*)d_in[6];
    const float* bih1  = (const float*)d_in[7];
    const float* bhh1  = (const float*)d_in[8];
    const float* Wlin  = (const float*)d_in[9];
    const float* blin  = (const float*)d_in[10];
    float* out = (float*)d_out;

    float* ws = (float*)d_ws;
    float* h0buf = ws;                       // 2 * 1024 * 64 floats (layer-0 h ping-pong)
    float* h2buf = ws + 2 * HID * BATCH;     // 2 * 1024 * 64 floats (layer-1 h ping-pong)
    uint32_t* flags = (uint32_t*)(ws + 4 * HID * BATCH);   // 512 u32

    lstm_fused<<<dim3(NBLK), dim3(NTHR), 0, stream>>>(
        x, Wih0, Whh0, bih0, bhh0, Wih1, Whh1, bih1, bhh1, out, h0buf, h2buf, flags);
    lstm_finalize<<<dim3(BATCH), dim3(256), 0, stream>>>(Wlin, blin, out, h2buf);
}

// Round 2
// 70550.085 us; speedup vs baseline: 1.7839x; 1.7839x over previous
//
#include <hip/hip_runtime.h>
#include <stdint.h>

#define SEQ   512
#define BATCH 64
#define INP   64
#define HID   1024
#define NBLK  512     // 256 layer-0 blocks + 256 layer-1 blocks (wavefront pipeline)
#define NTHR  256     // 4 units x 64 batch

// ---- agent-scope (sc0 sc1) coherent access: bypasses non-coherent per-XCD L2 ----
__device__ __forceinline__ float cload(float* p) {
    return __hip_atomic_load(p, __ATOMIC_RELAXED, __HIP_MEMORY_SCOPE_AGENT);
}
__device__ __forceinline__ void cstore(float* p, float v) {
    __hip_atomic_store(p, v, __ATOMIC_RELAXED, __HIP_MEMORY_SCOPE_AGENT);
}

// ---- FENCE-FREE grid barrier ----
// All cross-block data (h state) moves via agent-scope atomics, so no L2
// writeback/invalidate is needed. __syncthreads drains vmcnt(0) in every wave
// (compiler emits s_waitcnt vmcnt(0) before s_barrier), so all coherent h-stores
// are globally visible before tid0 publishes the flag with a relaxed store.
// Read-only weights/x stay cache-resident across ALL rounds (the round-1 fix).
__device__ __forceinline__ void gbar(uint32_t* flags, uint32_t val, int tid) {
    __syncthreads();
    if (tid == 0)
        __hip_atomic_store(&flags[blockIdx.x], val, __ATOMIC_RELAXED, __HIP_MEMORY_SCOPE_AGENT);
    if (tid < 64) {
        for (;;) {
            bool ok = true;
            #pragma unroll
            for (int i = 0; i < NBLK / 64; ++i) {
                uint32_t v = __hip_atomic_load(&flags[tid + i * 64], __ATOMIC_RELAXED,
                                               __HIP_MEMORY_SCOPE_AGENT);
                // pass iff val <= v < val + 2^28  (0xAAAAAAAA poison and stale values fail)
                ok &= ((uint32_t)(v - val) < 0x10000000u);
            }
            if (__all(ok)) break;
        }
    }
    __syncthreads();
}

__device__ __forceinline__ float sigf(float x) { return 1.0f / (1.0f + __expf(-x)); }

// ============ fused wavefront kernel ============
// blocks 0..255   : layer 0, computes step t at round t   (compute, then bar)
// blocks 256..511 : layer 1, computes step t at round t+1 (bar, then compute)
// h1_t is NOT parked in d_out: L1 reads it straight from L0's ping-pong slot
// h0buf[(t&1)^1] (same [k][b] layout, coalesced coherent dwords). d_out is
// written exactly once per (t,b,j) by L1 with plain cached stores.
__global__ void __launch_bounds__(NTHR, 2) lstm_fused(
    const float* __restrict__ x,
    const float* __restrict__ Wih0, const float* __restrict__ Whh0,
    const float* __restrict__ bih0, const float* __restrict__ bhh0,
    const float* __restrict__ Wih1, const float* __restrict__ Whh1,
    const float* __restrict__ bih1, const float* __restrict__ bhh1,
    float* __restrict__ out, float* __restrict__ h0buf, float* __restrict__ h2buf,
    uint32_t* __restrict__ flags)
{
    __shared__ float Wsh[4][HID][4];   // 64 KB: Whh0 (L0 blocks) or Whh1 (L1 blocks)
    const int tid = threadIdx.x;
    const int bk  = blockIdx.x;
    const bool L1 = (bk >= NBLK / 2);
    const int ub  = (L1 ? bk - NBLK / 2 : bk) * 4;                 // first unit of block
    const int u   = __builtin_amdgcn_readfirstlane(tid >> 6);      // wave-uniform unit idx
    const int b   = tid & 63;
    const int j   = ub + u;

    // stage recurrent weights into LDS (coalesced over k); cached loads, done once
    const float* Whh = L1 ? Whh1 : Whh0;
    for (int idx = tid; idx < 4 * 4 * HID; idx += NTHR) {
        int uu = idx >> 12, g = (idx >> 10) & 3, k = idx & (HID - 1);
        Wsh[uu][k][g] = Whh[((size_t)(g * HID + ub + uu)) * HID + k];
    }
    const float* bi = L1 ? bih1 : bih0;
    const float* bh = L1 ? bhh1 : bhh0;
    const float bias0 = bi[0 * HID + j] + bh[0 * HID + j];
    const float bias1 = bi[1 * HID + j] + bh[1 * HID + j];
    const float bias2 = bi[2 * HID + j] + bh[2 * HID + j];
    const float bias3 = bi[3 * HID + j] + bh[3 * HID + j];

    // h(-1) = 0 in slot 0 of this layer's ping-pong (ws is poisoned -> must init)
    cstore((L1 ? h2buf : h0buf) + j * 64 + b, 0.0f);
    float c = 0.0f;
    gbar(flags, 1u, tid);

    if (!L1) {
        // ---- layer 0: compute step t, then barrier(t+2) ----
        const float4* wi0 = (const float4*)(Wih0 + (size_t)(0 * HID + j) * INP);
        const float4* wi1 = (const float4*)(Wih0 + (size_t)(1 * HID + j) * INP);
        const float4* wi2 = (const float4*)(Wih0 + (size_t)(2 * HID + j) * INP);
        const float4* wi3 = (const float4*)(Wih0 + (size_t)(3 * HID + j) * INP);
        for (int t = 0; t < SEQ; ++t) {
            float a0 = bias0, a1 = bias1, a2 = bias2, a3 = bias3;
            const float4* xr = (const float4*)(x + ((size_t)t * BATCH + b) * INP);
            #pragma unroll
            for (int k4 = 0; k4 < INP / 4; ++k4) {
                float4 xv = xr[k4];                     // cached: x is read-only, L2-hot
                float4 u0 = wi0[k4], u1 = wi1[k4], u2 = wi2[k4], u3 = wi3[k4];
                a0 += u0.x * xv.x; a1 += u1.x * xv.x; a2 += u2.x * xv.x; a3 += u3.x * xv.x;
                a0 += u0.y * xv.y; a1 += u1.y * xv.y; a2 += u2.y * xv.y; a3 += u3.y * xv.y;
                a0 += u0.z * xv.z; a1 += u1.z * xv.z; a2 += u2.z * xv.z; a3 += u3.z * xv.z;
                a0 += u0.w * xv.w; a1 += u1.w * xv.w; a2 += u2.w * xv.w; a3 += u3.w * xv.w;
            }
            float* hr = h0buf + (t & 1) * (HID * 64);
            float* hw = h0buf + ((t & 1) ^ 1) * (HID * 64);
            #pragma unroll 16
            for (int k = 0; k < HID; ++k) {
                float  hv = cload(hr + k * 64 + b);     // coherent, coalesced (4 lines/instr)
                float4 w  = *(const float4*)&Wsh[u][k][0];
                a0 += w.x * hv; a1 += w.y * hv; a2 += w.z * hv; a3 += w.w * hv;
            }
            float ig = sigf(a0), fg = sigf(a1), gg = tanhf(a2), og = sigf(a3);
            c = fg * c + ig * gg;
            float h = og * tanhf(c);
            cstore(hw + j * 64 + b, h);                 // h1_t, read by both L0(t+1) and L1
            gbar(flags, (uint32_t)(t + 2), tid);
        }
    } else {
        // ---- layer 1: barrier(t+2) (waits for L0's step t), then compute step t ----
        // W_ih1 rows are wave-uniform, contiguous over k -> scalar-cache / L2 resident
        // (no per-round invalidation anymore, so they stay hot -- the round-1 fix)
        const float* wr0 = Wih1 + (size_t)(0 * HID + j) * HID;
        const float* wr1 = Wih1 + (size_t)(1 * HID + j) * HID;
        const float* wr2 = Wih1 + (size_t)(2 * HID + j) * HID;
        const float* wr3 = Wih1 + (size_t)(3 * HID + j) * HID;
        for (int t = 0; t < SEQ; ++t) {
            gbar(flags, (uint32_t)(t + 2), tid);
            float a0 = bias0, a1 = bias1, a2 = bias2, a3 = bias3;
            float* h1r = h0buf + ((t & 1) ^ 1) * (HID * 64);   // h1_t (L0 wrote last round)
            float* h2r = h2buf + (t & 1) * (HID * 64);
            float* h2w = h2buf + ((t & 1) ^ 1) * (HID * 64);
            #pragma unroll 16
            for (int k = 0; k < HID; ++k) {
                float x1 = cload(h1r + k * 64 + b);     // coherent, coalesced
                float hv = cload(h2r + k * 64 + b);     // coherent, coalesced
                float4 wh = *(const float4*)&Wsh[u][k][0];
                a0 += wh.x * hv + wr0[k] * x1;
                a1 += wh.y * hv + wr1[k] * x1;
                a2 += wh.z * hv + wr2[k] * x1;
                a3 += wh.w * hv + wr3[k] * x1;
            }
            float ig = sigf(a0), fg = sigf(a1), gg = tanhf(a2), og = sigf(a3);
            c = fg * c + ig * gg;
            float h = og * tanhf(c);
            cstore(h2w + j * 64 + b, h);                // recurrent state, coherent
            out[((size_t)t * BATCH + b) * HID + j] = h; // final output, plain cached store
            // no trailing barrier needed after t==SEQ-1: kernel end is the release
        }
    }
}

// ============ epilogue: y_pred = h2[T-1] @ Wlin^T + b ============
// h2[T-1] lives in h2buf slot 0 (((SEQ-1)&1)^1 == 0). Coherent loads dodge any
// stale L2 copies left by a previous graph-replay iteration of this kernel.
__global__ void lstm_finalize(const float* __restrict__ Wlin, const float* __restrict__ blin,
                              float* __restrict__ out, float* __restrict__ h2buf)
{
    __shared__ float red[256];
    const int b = blockIdx.x, tid = threadIdx.x;
    float p = 0.0f;
    for (int k = tid; k < HID; k += 256) p += cload(h2buf + k * 64 + b) * Wlin[k];
    red[tid] = p;
    __syncthreads();
    for (int s = 128; s > 0; s >>= 1) {
        if (tid < s) red[tid] += red[tid + s];
        __syncthreads();
    }
    if (tid == 0) out[(size_t)SEQ * BATCH * HID + b] = blin[0] + red[0];
}

extern "C" void kernel_launch(void* const* d_in, const int* in_sizes, int n_in,
                              void* d_out, int out_size, void* d_ws, size_t ws_size,
                              hipStream_t stream) {
    const float* x     = (const float*)d_in[0];
    const float* Wih0  = (const float*)d_in[1];
    const float* Whh0  = (const float*)d_in[2];
    const float* bih0  = (const float*)d_in[3];
    const float* bhh0  = (const float*)d_in[4];
    const float* Wih1  = (const float*)d_in[5];
    const float* Whh1  = (const float*)d_in[6];
    const float* bih1  = (const float*)d_in[7];
    const float* bhh1  = (const float*)d_in[8];
    const float* Wlin  = (const float*)d_in[9];
    const float* blin  = (const float*)d_in[10];
    float* out = (float*)d_out;

    float* ws = (float*)d_ws;
    float* h0buf = ws;                       // 2 * 1024 * 64 floats (layer-0 h ping-pong = h1)
    float* h2buf = ws + 2 * HID * BATCH;     // 2 * 1024 * 64 floats (layer-1 h ping-pong)
    uint32_t* flags = (uint32_t*)(ws + 4 * HID * BATCH);   // 512 u32

    lstm_fused<<<dim3(NBLK), dim3(NTHR), 0, stream>>>(
        x, Wih0, Whh0, bih0, bhh0, Wih1, Whh1, bih1, bhh1, out, h0buf, h2buf, flags);
    lstm_finalize<<<dim3(BATCH), dim3(256), 0, stream>>>(Wlin, blin, out, h2buf);
}

// Round 4
// 45014.200 us; speedup vs baseline: 2.7959x; 1.5673x over previous
//
#include <hip/hip_runtime.h>
#include <stdint.h>

#define SEQ   512
#define BATCH 64
#define INP   64
#define HID   1024
#define NBLK  512     // 256 layer-0 + 256 layer-1 blocks (wavefront pipeline)
#define NTHR  256     // 4 units x 64 batch  (256 blocks x 4 units = 1024 = HID, full cover)
#define CHK   32      // h k-values staged per chunk
#define NCH   (HID / CHK)
#define PRE   (CHK * 64 / NTHR)   // 8 floats per thread per stage buffer

// ---- agent-scope coherent access (bypasses non-coherent per-XCD L2) ----
__device__ __forceinline__ float cload(float* p) {
    return __hip_atomic_load(p, __ATOMIC_RELAXED, __HIP_MEMORY_SCOPE_AGENT);
}
__device__ __forceinline__ void cstore(float* p, float v) {
    __hip_atomic_store(p, v, __ATOMIC_RELAXED, __HIP_MEMORY_SCOPE_AGENT);
}

__device__ __forceinline__ float sigf(float x) { return 1.0f / (1.0f + __expf(-x)); }

// ---- one-time flag barrier (poison-safe window check, proven r2) ----
__device__ __forceinline__ void flagbar(uint32_t* flags, int tid) {
    __syncthreads();
    if (tid == 0)
        __hip_atomic_store(&flags[blockIdx.x], 1u, __ATOMIC_RELAXED, __HIP_MEMORY_SCOPE_AGENT);
    if (tid < 64) {
        for (;;) {
            bool ok = true;
            #pragma unroll
            for (int i = 0; i < NBLK / 64; ++i) {
                uint32_t v = __hip_atomic_load(&flags[tid + i * 64], __ATOMIC_RELAXED,
                                               __HIP_MEMORY_SCOPE_AGENT);
                ok &= ((uint32_t)(v - 1u) < 0x10000000u);
            }
            if (__all(ok)) break;
        }
    }
    __syncthreads();
}

// ---- per-round counter barrier: 8 monotonic group counters, no reset ----
// arrive: __syncthreads (drains all waves' coherent h-stores: vmcnt(0) before
// s_barrier) then one agent-scope atomicAdd by tid0. wait: ONE coherent load
// instr (64 lanes over 8 words). Target for barrier q is (q-1)*64; the window
// check tolerates overshoot from blocks already arrived at q+1 (monotonic).
__device__ __forceinline__ void bar_arrive(uint32_t* grp, int tid) {
    __syncthreads();
    if (tid == 0)
        __hip_atomic_fetch_add(&grp[blockIdx.x & 7], 1u, __ATOMIC_RELAXED,
                               __HIP_MEMORY_SCOPE_AGENT);
}
__device__ __forceinline__ void bar_wait(uint32_t* grp, uint32_t target, int tid) {
    if (tid < 64) {
        for (;;) {
            uint32_t v = __hip_atomic_load(&grp[tid & 7], __ATOMIC_RELAXED,
                                           __HIP_MEMORY_SCOPE_AGENT);
            if (__all((uint32_t)(v - target) < 0x10000000u)) break;
        }
    }
    __syncthreads();
}

// ============ fused wavefront kernel ============
// blocks 0..255   : layer 0, units 4*bk+u,       computes step t at round t
// blocks 256..511 : layer 1, units 4*(bk-256)+u, computes step t at round t+1
// h exchanged via ws ping-pong with coherent stores/loads; each block stages the
// full h vector through LDS in CHK-k chunks (coherent reads once per BLOCK, not
// per wave: 4x traffic cut vs r2) with next-chunk register prefetch (T14).
__global__ void __launch_bounds__(NTHR, 2) lstm_fused(
    const float* __restrict__ x,
    const float* __restrict__ Wih0, const float* __restrict__ Whh0,
    const float* __restrict__ bih0, const float* __restrict__ bhh0,
    const float* __restrict__ Wih1, const float* __restrict__ Whh1,
    const float* __restrict__ bih1, const float* __restrict__ bhh1,
    float* __restrict__ out, float* __restrict__ h0buf, float* __restrict__ h2buf,
    uint32_t* __restrict__ flags, uint32_t* __restrict__ grp)
{
    __shared__ float Wsh[4][HID][4];   // 64 KB: Whh slice (4 units x 4 gates)
    __shared__ float st1[CHK * 64];    // 8 KB: h0-chunk (L0) / h1-chunk (L1)
    __shared__ float st2[CHK * 64];    // 8 KB: h2-chunk (L1 only)
    const int tid = threadIdx.x;
    const int bk  = blockIdx.x;
    const bool Lb = (bk >= NBLK / 2);
    const int ub  = (Lb ? bk - NBLK / 2 : bk) * 4;
    const int u   = tid >> 6;
    const int b   = tid & 63;
    const int j   = ub + u;
    const int js  = ub + __builtin_amdgcn_readfirstlane(u);   // wave-uniform unit idx

    // stage recurrent weights into LDS (coalesced over k), once
    const float* Whh = Lb ? Whh1 : Whh0;
    for (int idx = tid; idx < 4 * 4 * HID; idx += NTHR) {
        int uu = idx >> 12, g = (idx >> 10) & 3, k = idx & (HID - 1);
        Wsh[uu][k][g] = Whh[((size_t)(g * HID + ub + uu)) * HID + k];
    }
    const float* bi = Lb ? bih1 : bih0;
    const float* bh = Lb ? bhh1 : bhh0;
    const float bias0 = bi[0 * HID + j] + bh[0 * HID + j];
    const float bias1 = bi[1 * HID + j] + bh[1 * HID + j];
    const float bias2 = bi[2 * HID + j] + bh[2 * HID + j];
    const float bias3 = bi[3 * HID + j] + bh[3 * HID + j];

    // h(-1) = 0 in slot 0 (ws poisoned); zero group counters before flag barrier
    cstore((Lb ? h2buf : h0buf) + j * 64 + b, 0.0f);
    if (bk < 8 && tid == 0) {
        __hip_atomic_store(&grp[bk], 0u, __ATOMIC_RELAXED, __HIP_MEMORY_SCOPE_AGENT);
        __threadfence();   // order ctr-zero before this block's flag post
    }
    float c = 0.0f;
    flagbar(flags, tid);   // barrier q=1

    if (!Lb) {
        // ---- layer 0: compute step t, arrive(t+2), xpart(t+1), wait(t+2) ----
        const float4* wi0 = (const float4*)(Wih0 + (size_t)(0 * HID + js) * INP);
        const float4* wi1 = (const float4*)(Wih0 + (size_t)(1 * HID + js) * INP);
        const float4* wi2 = (const float4*)(Wih0 + (size_t)(2 * HID + js) * INP);
        const float4* wi3 = (const float4*)(Wih0 + (size_t)(3 * HID + js) * INP);
        float a0 = bias0, a1 = bias1, a2 = bias2, a3 = bias3;
        {   // xpart(0)
            const float4* xr = (const float4*)(x + (size_t)b * INP);
            #pragma unroll
            for (int k4 = 0; k4 < INP / 4; ++k4) {
                float4 xv = xr[k4];
                float4 u0 = wi0[k4], u1 = wi1[k4], u2 = wi2[k4], u3 = wi3[k4];
                a0 += u0.x * xv.x + u0.y * xv.y + u0.z * xv.z + u0.w * xv.w;
                a1 += u1.x * xv.x + u1.y * xv.y + u1.z * xv.z + u1.w * xv.w;
                a2 += u2.x * xv.x + u2.y * xv.y + u2.z * xv.z + u2.w * xv.w;
                a3 += u3.x * xv.x + u3.y * xv.y + u3.z * xv.z + u3.w * xv.w;
            }
        }
        for (int t = 0; t < SEQ; ++t) {
            // invariant: wait(t+1) passed; a0..a3 = bias + xpart(t)
            float* hr = h0buf + (t & 1) * (HID * 64);
            float* hw = h0buf + ((t & 1) ^ 1) * (HID * 64);
            float pre[PRE];
            #pragma unroll
            for (int i = 0; i < PRE; ++i) pre[i] = cload(hr + i * NTHR + tid);
            for (int cc = 0; cc < NCH; ++cc) {
                __syncthreads();   // prev chunk fully consumed
                #pragma unroll
                for (int i = 0; i < PRE; ++i) st1[i * NTHR + tid] = pre[i];
                if (cc + 1 < NCH) {
                    float* src = hr + (cc + 1) * (CHK * 64);
                    #pragma unroll
                    for (int i = 0; i < PRE; ++i) pre[i] = cload(src + i * NTHR + tid);
                }
                __syncthreads();   // stage visible
                #pragma unroll
                for (int kk = 0; kk < CHK; ++kk) {
                    int k = cc * CHK + kk;
                    float  hv = st1[kk * 64 + b];
                    float4 w  = *(const float4*)&Wsh[u][k][0];
                    a0 += w.x * hv; a1 += w.y * hv; a2 += w.z * hv; a3 += w.w * hv;
                }
            }
            float ig = sigf(a0), fg = sigf(a1), gg = tanhf(a2), og = sigf(a3);
            c = fg * c + ig * gg;
            float h = og * tanhf(c);
            cstore(hw + j * 64 + b, h);          // h1_t: read by L0(t+1) and L1(t)
            bar_arrive(grp, tid);                // barrier q=t+2 (syncthreads drains cstore)
            if (t + 1 < SEQ) {
                // xpart(t+1): barrier-independent, overlaps the wait
                a0 = bias0; a1 = bias1; a2 = bias2; a3 = bias3;
                const float4* xr = (const float4*)(x + ((size_t)(t + 1) * BATCH + b) * INP);
                #pragma unroll
                for (int k4 = 0; k4 < INP / 4; ++k4) {
                    float4 xv = xr[k4];
                    float4 u0 = wi0[k4], u1 = wi1[k4], u2 = wi2[k4], u3 = wi3[k4];
                    a0 += u0.x * xv.x + u0.y * xv.y + u0.z * xv.z + u0.w * xv.w;
                    a1 += u1.x * xv.x + u1.y * xv.y + u1.z * xv.z + u1.w * xv.w;
                    a2 += u2.x * xv.x + u2.y * xv.y + u2.z * xv.z + u2.w * xv.w;
                    a3 += u3.x * xv.x + u3.y * xv.y + u3.z * xv.z + u3.w * xv.w;
                }
                bar_wait(grp, (uint32_t)(t + 1) * 64u, tid);   // wait q=t+2
            }
        }
    } else {
        // ---- layer 1: arrive(t+2), wait(t+2), compute step t ----
        const float* wr0 = Wih1 + (size_t)(0 * HID + js) * HID;   // wave-uniform rows
        const float* wr1 = Wih1 + (size_t)(1 * HID + js) * HID;
        const float* wr2 = Wih1 + (size_t)(2 * HID + js) * HID;
        const float* wr3 = Wih1 + (size_t)(3 * HID + js) * HID;
        for (int t = 0; t < SEQ; ++t) {
            bar_arrive(grp, tid);                          // h2[t-1] stores drained
            bar_wait(grp, (uint32_t)(t + 1) * 64u, tid);   // wait q=t+2 (h1_t visible)
            float* h1r = h0buf + ((t & 1) ^ 1) * (HID * 64);   // h1_t (L0 wrote this round)
            float* h2r = h2buf + (t & 1) * (HID * 64);
            float* h2w = h2buf + ((t & 1) ^ 1) * (HID * 64);
            float a0 = bias0, a1 = bias1, a2 = bias2, a3 = bias3;
            float p1[PRE], p2[PRE];
            #pragma unroll
            for (int i = 0; i < PRE; ++i) p1[i] = cload(h1r + i * NTHR + tid);
            #pragma unroll
            for (int i = 0; i < PRE; ++i) p2[i] = cload(h2r + i * NTHR + tid);
            for (int cc = 0; cc < NCH; ++cc) {
                __syncthreads();
                #pragma unroll
                for (int i = 0; i < PRE; ++i) st1[i * NTHR + tid] = p1[i];
                #pragma unroll
                for (int i = 0; i < PRE; ++i) st2[i * NTHR + tid] = p2[i];
                if (cc + 1 < NCH) {
                    float* s1 = h1r + (cc + 1) * (CHK * 64);
                    float* s2 = h2r + (cc + 1) * (CHK * 64);
                    #pragma unroll
                    for (int i = 0; i < PRE; ++i) p1[i] = cload(s1 + i * NTHR + tid);
                    #pragma unroll
                    for (int i = 0; i < PRE; ++i) p2[i] = cload(s2 + i * NTHR + tid);
                }
                __syncthreads();
                #pragma unroll
                for (int kk = 0; kk < CHK; ++kk) {
                    int k = cc * CHK + kk;
                    float  x1 = st1[kk * 64 + b];
                    float  hv = st2[kk * 64 + b];
                    float4 wh = *(const float4*)&Wsh[u][k][0];
                    a0 += wh.x * hv + wr0[k] * x1;
                    a1 += wh.y * hv + wr1[k] * x1;
                    a2 += wh.z * hv + wr2[k] * x1;
                    a3 += wh.w * hv + wr3[k] * x1;
                }
            }
            float ig = sigf(a0), fg = sigf(a1), gg = tanhf(a2), og = sigf(a3);
            c = fg * c + ig * gg;
            float h = og * tanhf(c);
            cstore(h2w + j * 64 + b, h);                // recurrent state, coherent
            out[((size_t)t * BATCH + b) * HID + j] = h; // final output, plain store
        }
    }
}

// ============ epilogue: y_pred = h2[T-1] @ Wlin^T + b ============
__global__ void lstm_finalize(const float* __restrict__ Wlin, const float* __restrict__ blin,
                              float* __restrict__ out, float* __restrict__ h2buf)
{
    __shared__ float red[256];
    const int b = blockIdx.x, tid = threadIdx.x;
    float p = 0.0f;
    for (int k = tid; k < HID; k += 256) p += cload(h2buf + k * 64 + b) * Wlin[k];
    red[tid] = p;
    __syncthreads();
    for (int s = 128; s > 0; s >>= 1) {
        if (tid < s) red[tid] += red[tid + s];
        __syncthreads();
    }
    if (tid == 0) out[(size_t)SEQ * BATCH * HID + b] = blin[0] + red[0];
}

extern "C" void kernel_launch(void* const* d_in, const int* in_sizes, int n_in,
                              void* d_out, int out_size, void* d_ws, size_t ws_size,
                              hipStream_t stream) {
    const float* x     = (const float*)d_in[0];
    const float* Wih0  = (const float*)d_in[1];
    const float* Whh0  = (const float*)d_in[2];
    const float* bih0  = (const float*)d_in[3];
    const float* bhh0  = (const float*)d_in[4];
    const float* Wih1  = (const float*)d_in[5];
    const float* Whh1  = (const float*)d_in[6];
    const float* bih1  = (const float*)d_in[7];
    const float* bhh1  = (const float*)d_in[8];
    const float* Wlin  = (const float*)d_in[9];
    const float* blin  = (const float*)d_in[10];
    float* out = (float*)d_out;

    float* ws = (float*)d_ws;
    float* h0buf = ws;                       // 2 * 1024 * 64 floats (layer-0 h ping-pong = h1)
    float* h2buf = ws + 2 * HID * BATCH;     // 2 * 1024 * 64 floats (layer-1 h ping-pong)
    uint32_t* flags = (uint32_t*)(ws + 4 * HID * BATCH);   // 512 u32 (init barrier)
    uint32_t* grp   = flags + NBLK;                         // 8 u32 (round counters)

    lstm_fused<<<dim3(NBLK), dim3(NTHR), 0, stream>>>(
        x, Wih0, Whh0, bih0, bhh0, Wih1, Whh1, bih1, bhh1, out, h0buf, h2buf, flags, grp);
    lstm_finalize<<<dim3(BATCH), dim3(256), 0, stream>>>(Wlin, blin, out, h2buf);
}